// Round 1
// baseline (851.428 us; speedup 1.0000x reference)
//
#include <hip/hip_runtime.h>
#include <hip/hip_bf16.h>

#define T_TOK 2048
#define H_DIM 1024
#define E_N   8
#define I_DIM 2048

#define BM 128
#define BN 128
#define BKQ 64
#define APAD 8
#define BPAD 2

typedef unsigned short u16;
typedef unsigned int   u32;

typedef __bf16 bf16_t;
typedef bf16_t bf16x8 __attribute__((ext_vector_type(8)));
typedef float  f32x4  __attribute__((ext_vector_type(4)));

union BF8U { u16 u[8]; bf16x8 v; };

__device__ __forceinline__ u16 f2bf(float f) {
    u32 u = __builtin_bit_cast(u32, f);
    u += 0x7FFFu + ((u >> 16) & 1u);   // RNE
    return (u16)(u >> 16);
}
__device__ __forceinline__ u32 pack2(float a, float b) {
    return (u32)f2bf(a) | ((u32)f2bf(b) << 16);
}

// ---------------- router: logits -> top2 -> normalized weights -> expert lists
__global__ __launch_bounds__(64) void router_k(
    const float* __restrict__ x, const float* __restrict__ rw,
    int* __restrict__ cnt, int* __restrict__ tok, float* __restrict__ wts)
{
    int t = blockIdx.x;
    int lane = threadIdx.x;
    const float* xr = x + (size_t)t * H_DIM;

    float acc[E_N];
#pragma unroll
    for (int e = 0; e < E_N; e++) acc[e] = 0.f;
    for (int j = 0; j < H_DIM / 64; j++) {
        float xv = xr[lane + 64 * j];
#pragma unroll
        for (int e = 0; e < E_N; e++)
            acc[e] += xv * rw[e * H_DIM + lane + 64 * j];
    }
#pragma unroll
    for (int e = 0; e < E_N; e++) {
        float v = acc[e];
        for (int off = 32; off; off >>= 1) v += __shfl_xor(v, off);
        acc[e] = v;
    }
    if (lane == 0) {
        int i0 = 0; float m0 = acc[0];
#pragma unroll
        for (int e = 1; e < E_N; e++) if (acc[e] > m0) { m0 = acc[e]; i0 = e; }
        int i1 = -1; float m1 = -INFINITY;
#pragma unroll
        for (int e = 0; e < E_N; e++) if (e != i0 && acc[e] > m1) { m1 = acc[e]; i1 = e; }
        // normalized top-2 softmax affinities (independent of other experts)
        float w0 = 1.f / (1.f + expf(m1 - m0));
        float w1 = 1.f - w0;
        int p0 = atomicAdd(&cnt[i0], 1);
        tok[i0 * T_TOK + p0] = t; wts[i0 * T_TOK + p0] = w0;
        int p1 = atomicAdd(&cnt[i1], 1);
        tok[i1 * T_TOK + p1] = t; wts[i1 * T_TOK + p1] = w1;
    }
}

__global__ void prefix_k(const int* __restrict__ cnt, int* __restrict__ offs)
{
    if (threadIdx.x == 0) {
        int s = 0;
        for (int e = 0; e < E_N; e++) { offs[e] = s; s += cnt[e]; }
        offs[E_N] = s;
    }
}

// ---------------- phase 3: act[slot][i] = silu(x@wg) * (x@wu), grouped by expert
__global__ __launch_bounds__(256, 2) void gateup_k(
    const float* __restrict__ x, const float* __restrict__ wg,
    const float* __restrict__ wu, const int* __restrict__ cnt,
    const int* __restrict__ offs, const int* __restrict__ tok,
    u16* __restrict__ act)
{
    int e    = blockIdx.x >> 4;
    int tile = blockIdx.x & 15;
    int row0 = tile * BM;
    int cntE = cnt[e];
    if (row0 >= cntE) return;
    int n0 = blockIdx.y * BN;
    int slot0 = offs[e] + row0;

    __shared__ u16 As[BM][BKQ + APAD];
    __shared__ u16 Bg[BKQ][BN + BPAD];
    __shared__ u16 Bu[BKQ][BN + BPAD];

    int tid = threadIdx.x;
    int arow = tid >> 1, ahalf = tid & 1;
    int grow = row0 + arow;
    int tt = (grow < cntE) ? tok[e * T_TOK + grow] : 0;
    const float* xrow = x + (size_t)tt * H_DIM + ahalf * 32;

    int brow = tid >> 2, bq = tid & 3;

    f32x4 accg[4][4], accu[4][4];
#pragma unroll
    for (int a = 0; a < 4; a++)
#pragma unroll
        for (int b = 0; b < 4; b++) { accg[a][b] = (f32x4)0.f; accu[a][b] = (f32x4)0.f; }

    int wid = tid >> 6, lane = tid & 63;
    int wm = wid >> 1, wn = wid & 1;
    int l15 = lane & 15, lg = lane >> 4;

    for (int k0 = 0; k0 < H_DIM; k0 += BKQ) {
        // stage A (gathered token rows), fp32 -> bf16
#pragma unroll
        for (int j = 0; j < 8; j++) {
            float4 v = *reinterpret_cast<const float4*>(xrow + k0 + j * 4);
            uint2 p; p.x = pack2(v.x, v.y); p.y = pack2(v.z, v.w);
            *reinterpret_cast<uint2*>(&As[arow][ahalf * 32 + j * 4]) = p;
        }
        // stage Bg / Bu
        const float* wgr = wg + ((size_t)e * H_DIM + (k0 + brow)) * I_DIM + n0 + bq * 32;
        const float* wur = wu + ((size_t)e * H_DIM + (k0 + brow)) * I_DIM + n0 + bq * 32;
#pragma unroll
        for (int j = 0; j < 8; j++) {
            float4 v = *reinterpret_cast<const float4*>(wgr + j * 4);
            *reinterpret_cast<u32*>(&Bg[brow][bq * 32 + j * 4])     = pack2(v.x, v.y);
            *reinterpret_cast<u32*>(&Bg[brow][bq * 32 + j * 4 + 2]) = pack2(v.z, v.w);
            float4 w = *reinterpret_cast<const float4*>(wur + j * 4);
            *reinterpret_cast<u32*>(&Bu[brow][bq * 32 + j * 4])     = pack2(w.x, w.y);
            *reinterpret_cast<u32*>(&Bu[brow][bq * 32 + j * 4 + 2]) = pack2(w.z, w.w);
        }
        __syncthreads();

#pragma unroll
        for (int ks = 0; ks < 2; ks++) {
            bf16x8 af[4];
            BF8U bgf[4], buf_[4];
#pragma unroll
            for (int mf = 0; mf < 4; mf++) {
                int r = wm * 64 + mf * 16 + l15;
                af[mf] = *reinterpret_cast<const bf16x8*>(&As[r][ks * 32 + lg * 8]);
            }
#pragma unroll
            for (int nf = 0; nf < 4; nf++) {
                int c = wn * 64 + nf * 16 + l15;
#pragma unroll
                for (int j = 0; j < 8; j++) {
                    int kk = ks * 32 + lg * 8 + j;
                    bgf[nf].u[j] = Bg[kk][c];
                    buf_[nf].u[j] = Bu[kk][c];
                }
            }
#pragma unroll
            for (int mf = 0; mf < 4; mf++)
#pragma unroll
                for (int nf = 0; nf < 4; nf++) {
                    accg[mf][nf] = __builtin_amdgcn_mfma_f32_16x16x32_bf16(af[mf], bgf[nf].v, accg[mf][nf], 0, 0, 0);
                    accu[mf][nf] = __builtin_amdgcn_mfma_f32_16x16x32_bf16(af[mf], buf_[nf].v, accu[mf][nf], 0, 0, 0);
                }
        }
        __syncthreads();
    }

    // epilogue: silu(g)*u -> bf16 act
#pragma unroll
    for (int mf = 0; mf < 4; mf++) {
#pragma unroll
        for (int j = 0; j < 4; j++) {
            int rl = wm * 64 + mf * 16 + lg * 4 + j;
            int gr = row0 + rl;
            if (gr < cntE) {
                size_t base = (size_t)(slot0 + rl) * I_DIM + n0;
#pragma unroll
                for (int nf = 0; nf < 4; nf++) {
                    float g = accg[mf][nf][j];
                    float u = accu[mf][nf][j];
                    float a = g / (1.f + expf(-g)) * u;
                    act[base + wn * 64 + nf * 16 + l15] = f2bf(a);
                }
            }
        }
    }
}

// ---------------- phase 4: out[t] += w * (act @ w_down[e])
__global__ __launch_bounds__(256, 2) void down_k(
    const u16* __restrict__ act, const float* __restrict__ wd,
    const int* __restrict__ cnt, const int* __restrict__ offs,
    const int* __restrict__ tok, const float* __restrict__ wts,
    float* __restrict__ out)
{
    int e    = blockIdx.x >> 4;
    int tile = blockIdx.x & 15;
    int row0 = tile * BM;
    int cntE = cnt[e];
    if (row0 >= cntE) return;
    int h0 = blockIdx.y * BN;
    int slot0 = offs[e] + row0;

    __shared__ u16 As[BM][BKQ + APAD];
    __shared__ u16 Bs[BKQ][BN + BPAD];

    int tid = threadIdx.x;
    int arow = tid >> 1, ahalf = tid & 1;
    int srow = slot0 + ((row0 + arow < cntE) ? arow : 0);
    const u16* arp = act + (size_t)srow * I_DIM + ahalf * 32;
    int brow = tid >> 2, bq = tid & 3;

    f32x4 acc[4][4];
#pragma unroll
    for (int a = 0; a < 4; a++)
#pragma unroll
        for (int b = 0; b < 4; b++) acc[a][b] = (f32x4)0.f;

    int wid = tid >> 6, lane = tid & 63;
    int wm = wid >> 1, wn = wid & 1;
    int l15 = lane & 15, lg = lane >> 4;

    for (int k0 = 0; k0 < I_DIM; k0 += BKQ) {
        // stage A (already bf16, contiguous slots)
#pragma unroll
        for (int j = 0; j < 4; j++) {
            uint4 v = *reinterpret_cast<const uint4*>(arp + k0 + j * 8);
            *reinterpret_cast<uint4*>(&As[arow][ahalf * 32 + j * 8]) = v;
        }
        // stage B = w_down[e][k][h], fp32 -> bf16
        const float* wdr = wd + ((size_t)e * I_DIM + (k0 + brow)) * H_DIM + h0 + bq * 32;
#pragma unroll
        for (int j = 0; j < 8; j++) {
            float4 v = *reinterpret_cast<const float4*>(wdr + j * 4);
            *reinterpret_cast<u32*>(&Bs[brow][bq * 32 + j * 4])     = pack2(v.x, v.y);
            *reinterpret_cast<u32*>(&Bs[brow][bq * 32 + j * 4 + 2]) = pack2(v.z, v.w);
        }
        __syncthreads();

#pragma unroll
        for (int ks = 0; ks < 2; ks++) {
            bf16x8 af[4];
            BF8U bf[4];
#pragma unroll
            for (int mf = 0; mf < 4; mf++) {
                int r = wm * 64 + mf * 16 + l15;
                af[mf] = *reinterpret_cast<const bf16x8*>(&As[r][ks * 32 + lg * 8]);
            }
#pragma unroll
            for (int nf = 0; nf < 4; nf++) {
                int c = wn * 64 + nf * 16 + l15;
#pragma unroll
                for (int j = 0; j < 8; j++)
                    bf[nf].u[j] = Bs[ks * 32 + lg * 8 + j][c];
            }
#pragma unroll
            for (int mf = 0; mf < 4; mf++)
#pragma unroll
                for (int nf = 0; nf < 4; nf++)
                    acc[mf][nf] = __builtin_amdgcn_mfma_f32_16x16x32_bf16(af[mf], bf[nf].v, acc[mf][nf], 0, 0, 0);
        }
        __syncthreads();
    }

    // epilogue: scale by affinity, atomic-add into out
#pragma unroll
    for (int mf = 0; mf < 4; mf++) {
#pragma unroll
        for (int j = 0; j < 4; j++) {
            int rl = wm * 64 + mf * 16 + lg * 4 + j;
            int gr = row0 + rl;
            if (gr < cntE) {
                float w = wts[e * T_TOK + gr];
                int t   = tok[e * T_TOK + gr];
                size_t base = (size_t)t * H_DIM + h0;
#pragma unroll
                for (int nf = 0; nf < 4; nf++) {
                    float v = acc[mf][nf][j] * w;
                    atomicAdd(&out[base + wn * 64 + nf * 16 + l15], v);
                }
            }
        }
    }
}

extern "C" void kernel_launch(void* const* d_in, const int* in_sizes, int n_in,
                              void* d_out, int out_size, void* d_ws, size_t ws_size,
                              hipStream_t stream)
{
    const float* x  = (const float*)d_in[0];
    const float* rw = (const float*)d_in[1];
    const float* wg = (const float*)d_in[2];
    const float* wu = (const float*)d_in[3];
    const float* wd = (const float*)d_in[4];
    float* out = (float*)d_out;

    char* ws = (char*)d_ws;
    int*   cnt  = (int*)ws;                          // 8 ints
    int*   offs = cnt + 8;                           // 9 ints
    int*   tok  = (int*)(ws + 128);                  // E*T ints  (64 KB)
    float* wts  = (float*)(ws + 128 + E_N * T_TOK * 4);
    u16*   act  = (u16*)(ws + 256 * 1024);           // 4096*2048 bf16 = 16 MB

    hipMemsetAsync(cnt, 0, 64, stream);
    hipMemsetAsync(out, 0, (size_t)T_TOK * H_DIM * sizeof(float), stream);

    router_k<<<T_TOK, 64, 0, stream>>>(x, rw, cnt, tok, wts);
    prefix_k<<<1, 64, 0, stream>>>(cnt, offs);
    gateup_k<<<dim3(E_N * 16, I_DIM / BN), 256, 0, stream>>>(x, wg, wu, cnt, offs, tok, act);
    down_k<<<dim3(E_N * 16, H_DIM / BN), 256, 0, stream>>>(act, wd, cnt, offs, tok, wts, out);
}

// Round 2
// 378.613 us; speedup vs baseline: 2.2488x; 2.2488x over previous
//
#include <hip/hip_runtime.h>
#include <hip/hip_bf16.h>

#define T_TOK 2048
#define H_DIM 1024
#define E_N   8
#define I_DIM 2048

#define MAX_TILES 72      // sum ceil(cnt_e/64) <= 4096/64 + 8
#define MAX_SLOTS 4608    // padded slot upper bound

typedef unsigned short u16;
typedef unsigned int   u32;
typedef __bf16 bf16_t;
typedef bf16_t bf16x8 __attribute__((ext_vector_type(8)));
typedef u16    u16x8  __attribute__((ext_vector_type(8)));
typedef float  f32x4  __attribute__((ext_vector_type(4)));

#define MFMA __builtin_amdgcn_mfma_f32_16x16x32_bf16

__device__ __forceinline__ u16 bfbits(float f) {
    bf16_t b = (bf16_t)f;                 // compiler emits v_cvt_pk_bf16_f32 pairs
    return __builtin_bit_cast(u16, b);
}

// swizzled LDS offset (u16 elems) for transposed B tile: row n (0..127), k-block kb (0..7)
__device__ __forceinline__ int bt_off(int n, int kb) {
    return n * 72 + ((kb ^ ((n >> 2) & 7)) << 3);
}

// ---------------- x fp32 -> bf16
__global__ __launch_bounds__(256) void cvt_x_k(const float* __restrict__ x, u16* __restrict__ xbf)
{
    int i = (blockIdx.x * 256 + threadIdx.x) * 8;
    float4 a = *reinterpret_cast<const float4*>(x + i);
    float4 b = *reinterpret_cast<const float4*>(x + i + 4);
    u16x8 p;
    p[0]=bfbits(a.x); p[1]=bfbits(a.y); p[2]=bfbits(a.z); p[3]=bfbits(a.w);
    p[4]=bfbits(b.x); p[5]=bfbits(b.y); p[6]=bfbits(b.z); p[7]=bfbits(b.w);
    *reinterpret_cast<u16x8*>(xbf + i) = p;
}

// ---------------- router: logits -> top2 -> normalized weights -> expert lists
__global__ __launch_bounds__(64) void router_k(
    const float* __restrict__ x, const float* __restrict__ rw,
    int* __restrict__ cnt, int* __restrict__ tok, float* __restrict__ wts)
{
    int t = blockIdx.x;
    int lane = threadIdx.x;
    const float* xr = x + (size_t)t * H_DIM;

    float acc[E_N];
#pragma unroll
    for (int e = 0; e < E_N; e++) acc[e] = 0.f;
    for (int j = 0; j < H_DIM / 64; j++) {
        float xv = xr[lane + 64 * j];
#pragma unroll
        for (int e = 0; e < E_N; e++)
            acc[e] += xv * rw[e * H_DIM + lane + 64 * j];
    }
#pragma unroll
    for (int e = 0; e < E_N; e++) {
        float v = acc[e];
        for (int off = 32; off; off >>= 1) v += __shfl_xor(v, off);
        acc[e] = v;
    }
    if (lane == 0) {
        int i0 = 0; float m0 = acc[0];
#pragma unroll
        for (int e = 1; e < E_N; e++) if (acc[e] > m0) { m0 = acc[e]; i0 = e; }
        int i1 = -1; float m1 = -INFINITY;
#pragma unroll
        for (int e = 0; e < E_N; e++) if (e != i0 && acc[e] > m1) { m1 = acc[e]; i1 = e; }
        float w0 = 1.f / (1.f + expf(m1 - m0));
        float w1 = 1.f - w0;
        int p0 = atomicAdd(&cnt[i0], 1);
        tok[i0 * T_TOK + p0] = t; wts[i0 * T_TOK + p0] = w0;
        int p1 = atomicAdd(&cnt[i1], 1);
        tok[i1 * T_TOK + p1] = t; wts[i1 * T_TOK + p1] = w1;
    }
}

// ---------------- prefix + padded tile map
__global__ void prefix_k(const int* __restrict__ cnt, int* __restrict__ offs_pad,
                         int* __restrict__ tile_e, int* __restrict__ tile_row0,
                         int* __restrict__ ntiles)
{
    if (threadIdx.x == 0) {
        int s = 0, nt = 0;
        for (int e = 0; e < E_N; e++) {
            offs_pad[e] = s;
            int c = cnt[e];
            int t = (c + 63) >> 6;
            for (int i = 0; i < t; i++) { tile_e[nt] = e; tile_row0[nt] = i * 64; nt++; }
            s += t * 64;
        }
        offs_pad[E_N] = s;
        *ntiles = nt;
    }
}

// ---------------- gate/up grouped GEMM: act[slot][i] = silu(x@wg)*(x@wu)
// tile: 64 rows x 128 cols, BK=64, 4 waves (2M x 2N), wave tile 32x64 per matrix
__global__ __launch_bounds__(256, 2) void gateup_k(
    const u16* __restrict__ xbf, const float* __restrict__ wg, const float* __restrict__ wu,
    const int* __restrict__ cnt, const int* __restrict__ offs_pad,
    const int* __restrict__ tile_e, const int* __restrict__ tile_row0,
    const int* __restrict__ ntiles, const int* __restrict__ tok,
    u16* __restrict__ act)
{
    int tb = blockIdx.x;
    if (tb >= *ntiles) return;
    int e = tile_e[tb], row0 = tile_row0[tb];
    int cntE = cnt[e];
    int n0 = blockIdx.y * 128;
    int slot0 = offs_pad[e] + row0;

    __shared__ u16 BT[2][128 * 72];   // transposed+swizzled bf16 W tiles

    int tid = threadIdx.x;
    int lane = tid & 63, wid = tid >> 6;
    int wm = wid >> 1, wn = wid & 1;
    int l15 = lane & 15, lg = lane >> 4;

    // A rows direct from global (bf16 x), hoisted
    const u16* arow[2];
#pragma unroll
    for (int mf = 0; mf < 2; mf++) {
        int rr = row0 + wm * 32 + mf * 16 + l15;
        int rc = rr < cntE ? rr : cntE - 1;
        arow[mf] = xbf + (size_t)tok[e * T_TOK + rc] * H_DIM;
    }

    int nq = tid & 31;            // n quad
    int kb = tid >> 5;            // k block (8 k each)
    int sn = nq * 4;

    f32x4 accg[2][4], accu[2][4];
#pragma unroll
    for (int a = 0; a < 2; a++)
#pragma unroll
        for (int b = 0; b < 4; b++) { accg[a][b] = (f32x4)0.f; accu[a][b] = (f32x4)0.f; }

    for (int k0 = 0; k0 < H_DIM; k0 += 64) {
#pragma unroll
        for (int mat = 0; mat < 2; mat++) {
            const float* W = mat ? wu : wg;
            const float* src = W + ((size_t)e * H_DIM + (k0 + kb * 8)) * I_DIM + n0 + sn;
            float4 v[8];
#pragma unroll
            for (int i = 0; i < 8; i++) v[i] = *reinterpret_cast<const float4*>(src + (size_t)i * I_DIM);
#pragma unroll
            for (int c = 0; c < 4; c++) {
                u16x8 p;
#pragma unroll
                for (int i = 0; i < 8; i++) {
                    float f = (c == 0) ? v[i].x : (c == 1) ? v[i].y : (c == 2) ? v[i].z : v[i].w;
                    p[i] = bfbits(f);
                }
                *reinterpret_cast<u16x8*>(&BT[mat][bt_off(sn + c, kb)]) = p;
            }
        }
        __syncthreads();

#pragma unroll
        for (int ks = 0; ks < 2; ks++) {
            bf16x8 af[2];
#pragma unroll
            for (int mf = 0; mf < 2; mf++)
                af[mf] = *reinterpret_cast<const bf16x8*>(arow[mf] + k0 + ks * 32 + lg * 8);
            int kbr = ks * 4 + lg;
#pragma unroll
            for (int nf = 0; nf < 4; nf++) {
                int c = wn * 64 + nf * 16 + l15;
                bf16x8 bg = *reinterpret_cast<const bf16x8*>(&BT[0][bt_off(c, kbr)]);
                bf16x8 bu = *reinterpret_cast<const bf16x8*>(&BT[1][bt_off(c, kbr)]);
#pragma unroll
                for (int mf = 0; mf < 2; mf++) {
                    accg[mf][nf] = MFMA(af[mf], bg, accg[mf][nf], 0, 0, 0);
                    accu[mf][nf] = MFMA(af[mf], bu, accu[mf][nf], 0, 0, 0);
                }
            }
        }
        __syncthreads();
    }

    // epilogue: silu(g)*u -> bf16; padded rows -> 0 (down_k reads them)
#pragma unroll
    for (int mf = 0; mf < 2; mf++)
#pragma unroll
        for (int j = 0; j < 4; j++) {
            int rl = wm * 32 + mf * 16 + lg * 4 + j;
            bool valid = (row0 + rl) < cntE;
            size_t base = (size_t)(slot0 + rl) * I_DIM + n0;
#pragma unroll
            for (int nf = 0; nf < 4; nf++) {
                float g = accg[mf][nf][j];
                float u = accu[mf][nf][j];
                float a = valid ? (g / (1.f + expf(-g))) * u : 0.f;
                act[base + wn * 64 + nf * 16 + l15] = bfbits(a);
            }
        }
}

// ---------------- down grouped GEMM: out[t] += w * (act @ w_down[e])
__global__ __launch_bounds__(256, 2) void down_k(
    const u16* __restrict__ act, const float* __restrict__ wd,
    const int* __restrict__ cnt, const int* __restrict__ offs_pad,
    const int* __restrict__ tile_e, const int* __restrict__ tile_row0,
    const int* __restrict__ ntiles, const int* __restrict__ tok,
    const float* __restrict__ wts, float* __restrict__ out)
{
    int tb = blockIdx.x;
    if (tb >= *ntiles) return;
    int e = tile_e[tb], row0 = tile_row0[tb];
    int cntE = cnt[e];
    int h0 = blockIdx.y * 128;
    int slot0 = offs_pad[e] + row0;

    __shared__ u16 BT[128 * 72];

    int tid = threadIdx.x;
    int lane = tid & 63, wid = tid >> 6;
    int wm = wid >> 1, wn = wid & 1;
    int l15 = lane & 15, lg = lane >> 4;

    const u16* arow[2];
#pragma unroll
    for (int mf = 0; mf < 2; mf++)
        arow[mf] = act + (size_t)(slot0 + wm * 32 + mf * 16 + l15) * I_DIM;

    int nq = tid & 31;
    int kb = tid >> 5;
    int sn = nq * 4;

    f32x4 acc[2][4];
#pragma unroll
    for (int a = 0; a < 2; a++)
#pragma unroll
        for (int b = 0; b < 4; b++) acc[a][b] = (f32x4)0.f;

    for (int k0 = 0; k0 < I_DIM; k0 += 64) {
        const float* src = wd + ((size_t)e * I_DIM + (k0 + kb * 8)) * H_DIM + h0 + sn;
        float4 v[8];
#pragma unroll
        for (int i = 0; i < 8; i++) v[i] = *reinterpret_cast<const float4*>(src + (size_t)i * H_DIM);
#pragma unroll
        for (int c = 0; c < 4; c++) {
            u16x8 p;
#pragma unroll
            for (int i = 0; i < 8; i++) {
                float f = (c == 0) ? v[i].x : (c == 1) ? v[i].y : (c == 2) ? v[i].z : v[i].w;
                p[i] = bfbits(f);
            }
            *reinterpret_cast<u16x8*>(&BT[bt_off(sn + c, kb)]) = p;
        }
        __syncthreads();

#pragma unroll
        for (int ks = 0; ks < 2; ks++) {
            bf16x8 af[2];
#pragma unroll
            for (int mf = 0; mf < 2; mf++)
                af[mf] = *reinterpret_cast<const bf16x8*>(arow[mf] + k0 + ks * 32 + lg * 8);
            int kbr = ks * 4 + lg;
#pragma unroll
            for (int nf = 0; nf < 4; nf++) {
                int c = wn * 64 + nf * 16 + l15;
                bf16x8 bfr = *reinterpret_cast<const bf16x8*>(&BT[bt_off(c, kbr)]);
#pragma unroll
                for (int mf = 0; mf < 2; mf++)
                    acc[mf][nf] = MFMA(af[mf], bfr, acc[mf][nf], 0, 0, 0);
            }
        }
        __syncthreads();
    }

#pragma unroll
    for (int mf = 0; mf < 2; mf++)
#pragma unroll
        for (int j = 0; j < 4; j++) {
            int rl = wm * 32 + mf * 16 + lg * 4 + j;
            int gr = row0 + rl;
            if (gr < cntE) {
                float w = wts[e * T_TOK + gr];
                int t   = tok[e * T_TOK + gr];
                size_t base = (size_t)t * H_DIM + h0;
#pragma unroll
                for (int nf = 0; nf < 4; nf++)
                    atomicAdd(&out[base + wn * 64 + nf * 16 + l15], acc[mf][nf][j] * w);
            }
        }
}

extern "C" void kernel_launch(void* const* d_in, const int* in_sizes, int n_in,
                              void* d_out, int out_size, void* d_ws, size_t ws_size,
                              hipStream_t stream)
{
    const float* x  = (const float*)d_in[0];
    const float* rw = (const float*)d_in[1];
    const float* wg = (const float*)d_in[2];
    const float* wu = (const float*)d_in[3];
    const float* wd = (const float*)d_in[4];
    float* out = (float*)d_out;

    char* ws = (char*)d_ws;
    int*   cnt       = (int*)(ws);
    int*   ntiles    = (int*)(ws + 32);
    int*   offs_pad  = (int*)(ws + 64);
    int*   tile_e    = (int*)(ws + 128);
    int*   tile_row0 = (int*)(ws + 128 + MAX_TILES * 4);
    int*   tok       = (int*)(ws + 4096);
    float* wts       = (float*)(ws + 4096 + T_TOK * E_N * 4);
    u16*   xbf       = (u16*)(ws + 256 * 1024);
    u16*   act       = (u16*)(ws + 8 * 1024 * 1024);

    size_t need = 8ull * 1024 * 1024 + (size_t)MAX_SLOTS * I_DIM * 2;
    if (ws_size < need) return;   // fail visibly rather than corrupt

    hipMemsetAsync(cnt, 0, 32, stream);
    hipMemsetAsync(out, 0, (size_t)T_TOK * H_DIM * sizeof(float), stream);

    cvt_x_k<<<T_TOK * H_DIM / (256 * 8), 256, 0, stream>>>(x, xbf);
    router_k<<<T_TOK, 64, 0, stream>>>(x, rw, cnt, tok, wts);
    prefix_k<<<1, 64, 0, stream>>>(cnt, offs_pad, tile_e, tile_row0, ntiles);
    gateup_k<<<dim3(MAX_TILES, I_DIM / 128), 256, 0, stream>>>(
        xbf, wg, wu, cnt, offs_pad, tile_e, tile_row0, ntiles, tok, act);
    down_k<<<dim3(MAX_TILES, H_DIM / 128), 256, 0, stream>>>(
        act, wd, cnt, offs_pad, tile_e, tile_row0, ntiles, tok, wts, out);
}

// Round 3
// 245.694 us; speedup vs baseline: 3.4654x; 1.5410x over previous
//
#include <hip/hip_runtime.h>
#include <hip/hip_bf16.h>

#define T_TOK 2048
#define H_DIM 1024
#define E_N   8
#define I_DIM 2048

#define NT_MAX 40         // sum ceil(cnt_e/128) <= 4096/128 + 7 = 39
#define MAX_SLOTS 5120    // 40 tiles * 128 rows

typedef unsigned short u16;
typedef unsigned int   u32;
typedef __bf16 bf16_t;
typedef bf16_t bf16x8 __attribute__((ext_vector_type(8)));
typedef u16    u16x8  __attribute__((ext_vector_type(8)));
typedef float  f32x4  __attribute__((ext_vector_type(4)));

#define MFMA __builtin_amdgcn_mfma_f32_16x16x32_bf16

__device__ __forceinline__ u16 bfbits(float f) {
    bf16_t b = (bf16_t)f;
    return __builtin_bit_cast(u16, b);
}

// swizzled LDS offset (u16 elems) for transposed B tile: row n (0..127), k-block kb (0..7)
__device__ __forceinline__ int bt_off(int n, int kb) {
    return n * 72 + ((kb ^ ((n >> 2) & 7)) << 3);
}

// ---------------- router: logits -> top2 -> normalized weights -> expert lists
// (also converts this token's x row to bf16)
__global__ __launch_bounds__(64) void router_k(
    const float* __restrict__ x, const float* __restrict__ rw,
    int* __restrict__ cnt, int* __restrict__ tok, float* __restrict__ wts,
    u16* __restrict__ xbf)
{
    int t = blockIdx.x;
    int lane = threadIdx.x;
    const float* xr = x + (size_t)t * H_DIM;
    u16* xbr = xbf + (size_t)t * H_DIM;

    float acc[E_N];
#pragma unroll
    for (int e = 0; e < E_N; e++) acc[e] = 0.f;
    for (int j = 0; j < H_DIM / 64; j++) {
        float xv = xr[lane + 64 * j];
        xbr[lane + 64 * j] = bfbits(xv);
#pragma unroll
        for (int e = 0; e < E_N; e++)
            acc[e] += xv * rw[e * H_DIM + lane + 64 * j];
    }
#pragma unroll
    for (int e = 0; e < E_N; e++) {
        float v = acc[e];
        for (int off = 32; off; off >>= 1) v += __shfl_xor(v, off);
        acc[e] = v;
    }
    if (lane == 0) {
        int i0 = 0; float m0 = acc[0];
#pragma unroll
        for (int e = 1; e < E_N; e++) if (acc[e] > m0) { m0 = acc[e]; i0 = e; }
        int i1 = -1; float m1 = -INFINITY;
#pragma unroll
        for (int e = 0; e < E_N; e++) if (e != i0 && acc[e] > m1) { m1 = acc[e]; i1 = e; }
        float w0 = 1.f / (1.f + expf(m1 - m0));
        float w1 = 1.f - w0;
        int p0 = atomicAdd(&cnt[i0], 1);
        tok[i0 * T_TOK + p0] = t; wts[i0 * T_TOK + p0] = w0;
        int p1 = atomicAdd(&cnt[i1], 1);
        tok[i1 * T_TOK + p1] = t; wts[i1 * T_TOK + p1] = w1;
    }
}

// ---------------- prefix + padded tile map (BM=128)
__global__ void prefix_k(const int* __restrict__ cnt, int* __restrict__ offs_pad,
                         int* __restrict__ tile_e, int* __restrict__ tile_row0,
                         int* __restrict__ ntiles)
{
    if (threadIdx.x == 0) {
        int s = 0, nt = 0;
        for (int e = 0; e < E_N; e++) {
            offs_pad[e] = s;
            int c = cnt[e];
            int t = (c + 127) >> 7;
            for (int i = 0; i < t; i++) { tile_e[nt] = e; tile_row0[nt] = i * 128; nt++; }
            s += t * 128;
        }
        offs_pad[E_N] = s;
        *ntiles = nt;
    }
}

// ---------------- gate/up grouped GEMM: act[slot][i] = silu(x@wg)*(x@wu)
// tile 128x128, BK=64, 4 waves (2Mx2N), wave tile 64x64 per matrix, dbuf LDS
__global__ __launch_bounds__(256, 2) void gateup_k(
    const u16* __restrict__ xbf, const float* __restrict__ wg, const float* __restrict__ wu,
    const int* __restrict__ cnt, const int* __restrict__ offs_pad,
    const int* __restrict__ tile_e, const int* __restrict__ tile_row0,
    const int* __restrict__ ntiles, const int* __restrict__ tok,
    u16* __restrict__ act)
{
    // chunked XCD swizzle: consecutive logicals (tb fastest) land on one XCD
    int q = gridDim.x >> 3;
    int phys = blockIdx.x;
    int logical = (phys & 7) * q + (phys >> 3);
    int tb = logical % NT_MAX;
    int n0 = (logical / NT_MAX) * 128;
    if (tb >= *ntiles) return;
    int e = tile_e[tb], row0 = tile_row0[tb];
    int cntE = cnt[e];
    int slot0 = offs_pad[e] + row0;

    __shared__ u16 BT[2][2][128 * 72];   // [buf][mat][...]

    int tid = threadIdx.x;
    int lane = tid & 63, wid = tid >> 6;
    int wm = wid >> 1, wn = wid & 1;
    int l15 = lane & 15, lg = lane >> 4;

    // A row pointers (gathered tokens), clamped
    const u16* arow[4];
#pragma unroll
    for (int mf = 0; mf < 4; mf++) {
        int rr = row0 + wm * 64 + mf * 16 + l15;
        int rc = rr < cntE ? rr : cntE - 1;
        arow[mf] = xbf + (size_t)tok[e * T_TOK + rc] * H_DIM;
    }

    int nq = tid & 31;            // n-quad: cols sn..sn+3
    int kb = tid >> 5;            // k-block: rows kb*8..kb*8+7
    int sn = nq * 4;

    const float* gptr = wg + ((size_t)e * H_DIM + kb * 8) * I_DIM + n0 + sn;
    const float* uptr = wu + ((size_t)e * H_DIM + kb * 8) * I_DIM + n0 + sn;

    float4 vg[8], vu[8];
#pragma unroll
    for (int i = 0; i < 8; i++) {
        vg[i] = *reinterpret_cast<const float4*>(gptr + (size_t)i * I_DIM);
        vu[i] = *reinterpret_cast<const float4*>(uptr + (size_t)i * I_DIM);
    }

    f32x4 accg[4][4], accu[4][4];
#pragma unroll
    for (int a = 0; a < 4; a++)
#pragma unroll
        for (int b = 0; b < 4; b++) { accg[a][b] = (f32x4)0.f; accu[a][b] = (f32x4)0.f; }

    for (int k0 = 0; k0 < H_DIM; k0 += 64) {
        int buf = (k0 >> 6) & 1;
        // convert staged regs (data for k0) -> LDS
#pragma unroll
        for (int c = 0; c < 4; c++) {
            u16x8 p;
#pragma unroll
            for (int i = 0; i < 8; i++) {
                float f = (c == 0) ? vg[i].x : (c == 1) ? vg[i].y : (c == 2) ? vg[i].z : vg[i].w;
                p[i] = bfbits(f);
            }
            *reinterpret_cast<u16x8*>(&BT[buf][0][bt_off(sn + c, kb)]) = p;
        }
#pragma unroll
        for (int c = 0; c < 4; c++) {
            u16x8 p;
#pragma unroll
            for (int i = 0; i < 8; i++) {
                float f = (c == 0) ? vu[i].x : (c == 1) ? vu[i].y : (c == 2) ? vu[i].z : vu[i].w;
                p[i] = bfbits(f);
            }
            *reinterpret_cast<u16x8*>(&BT[buf][1][bt_off(sn + c, kb)]) = p;
        }
        // issue next tile's loads (overlap with this tile's MFMA)
        if (k0 + 64 < H_DIM) {
#pragma unroll
            for (int i = 0; i < 8; i++) {
                vg[i] = *reinterpret_cast<const float4*>(gptr + (size_t)(k0 + 64 + i) * I_DIM);
                vu[i] = *reinterpret_cast<const float4*>(uptr + (size_t)(k0 + 64 + i) * I_DIM);
            }
        }
        __syncthreads();

#pragma unroll
        for (int ks = 0; ks < 2; ks++) {
            bf16x8 af[4];
#pragma unroll
            for (int mf = 0; mf < 4; mf++)
                af[mf] = *reinterpret_cast<const bf16x8*>(arow[mf] + k0 + ks * 32 + lg * 8);
            int kbr = ks * 4 + lg;
#pragma unroll
            for (int nf = 0; nf < 4; nf++) {
                int c = wn * 64 + nf * 16 + l15;
                bf16x8 bg = *reinterpret_cast<const bf16x8*>(&BT[buf][0][bt_off(c, kbr)]);
                bf16x8 bu = *reinterpret_cast<const bf16x8*>(&BT[buf][1][bt_off(c, kbr)]);
#pragma unroll
                for (int mf = 0; mf < 4; mf++) {
                    accg[mf][nf] = MFMA(af[mf], bg, accg[mf][nf], 0, 0, 0);
                    accu[mf][nf] = MFMA(af[mf], bu, accu[mf][nf], 0, 0, 0);
                }
            }
        }
        // no trailing barrier: double buffer + next iter's barrier order the reuse
    }

    // epilogue: silu(g)*u -> bf16; padded rows -> 0 (down_k reads them)
#pragma unroll
    for (int mf = 0; mf < 4; mf++)
#pragma unroll
        for (int j = 0; j < 4; j++) {
            int rl = wm * 64 + mf * 16 + lg * 4 + j;
            bool valid = (row0 + rl) < cntE;
            size_t base = (size_t)(slot0 + rl) * I_DIM + n0;
#pragma unroll
            for (int nf = 0; nf < 4; nf++) {
                float g = accg[mf][nf][j];
                float u = accu[mf][nf][j];
                float a = valid ? (g / (1.f + expf(-g))) * u : 0.f;
                act[base + wn * 64 + nf * 16 + l15] = bfbits(a);
            }
        }
}

// ---------------- down grouped GEMM: out[t] += w * (act @ w_down[e])
__global__ __launch_bounds__(256, 2) void down_k(
    const u16* __restrict__ act, const float* __restrict__ wd,
    const int* __restrict__ cnt, const int* __restrict__ offs_pad,
    const int* __restrict__ tile_e, const int* __restrict__ tile_row0,
    const int* __restrict__ ntiles, const int* __restrict__ tok,
    const float* __restrict__ wts, float* __restrict__ out)
{
    int q = gridDim.x >> 3;
    int phys = blockIdx.x;
    int logical = (phys & 7) * q + (phys >> 3);
    int tb = logical % NT_MAX;
    int h0 = (logical / NT_MAX) * 128;
    if (tb >= *ntiles) return;
    int e = tile_e[tb], row0 = tile_row0[tb];
    int cntE = cnt[e];
    int slot0 = offs_pad[e] + row0;

    __shared__ u16 BT[2][128 * 72];

    int tid = threadIdx.x;
    int lane = tid & 63, wid = tid >> 6;
    int wm = wid >> 1, wn = wid & 1;
    int l15 = lane & 15, lg = lane >> 4;

    const u16* arow[4];
#pragma unroll
    for (int mf = 0; mf < 4; mf++)
        arow[mf] = act + (size_t)(slot0 + wm * 64 + mf * 16 + l15) * I_DIM;

    int nq = tid & 31;
    int kb = tid >> 5;
    int sn = nq * 4;

    const float* dptr = wd + ((size_t)e * I_DIM + kb * 8) * H_DIM + h0 + sn;

    float4 vd[8];
#pragma unroll
    for (int i = 0; i < 8; i++)
        vd[i] = *reinterpret_cast<const float4*>(dptr + (size_t)i * H_DIM);

    f32x4 acc[4][4];
#pragma unroll
    for (int a = 0; a < 4; a++)
#pragma unroll
        for (int b = 0; b < 4; b++) acc[a][b] = (f32x4)0.f;

    for (int k0 = 0; k0 < I_DIM; k0 += 64) {
        int buf = (k0 >> 6) & 1;
#pragma unroll
        for (int c = 0; c < 4; c++) {
            u16x8 p;
#pragma unroll
            for (int i = 0; i < 8; i++) {
                float f = (c == 0) ? vd[i].x : (c == 1) ? vd[i].y : (c == 2) ? vd[i].z : vd[i].w;
                p[i] = bfbits(f);
            }
            *reinterpret_cast<u16x8*>(&BT[buf][bt_off(sn + c, kb)]) = p;
        }
        if (k0 + 64 < I_DIM) {
#pragma unroll
            for (int i = 0; i < 8; i++)
                vd[i] = *reinterpret_cast<const float4*>(dptr + (size_t)(k0 + 64 + i) * H_DIM);
        }
        __syncthreads();

#pragma unroll
        for (int ks = 0; ks < 2; ks++) {
            bf16x8 af[4];
#pragma unroll
            for (int mf = 0; mf < 4; mf++)
                af[mf] = *reinterpret_cast<const bf16x8*>(arow[mf] + k0 + ks * 32 + lg * 8);
            int kbr = ks * 4 + lg;
#pragma unroll
            for (int nf = 0; nf < 4; nf++) {
                int c = wn * 64 + nf * 16 + l15;
                bf16x8 bfr = *reinterpret_cast<const bf16x8*>(&BT[buf][bt_off(c, kbr)]);
#pragma unroll
                for (int mf = 0; mf < 4; mf++)
                    acc[mf][nf] = MFMA(af[mf], bfr, acc[mf][nf], 0, 0, 0);
            }
        }
    }

#pragma unroll
    for (int mf = 0; mf < 4; mf++)
#pragma unroll
        for (int j = 0; j < 4; j++) {
            int rl = wm * 64 + mf * 16 + lg * 4 + j;
            int gr = row0 + rl;
            if (gr < cntE) {
                float w = wts[e * T_TOK + gr];
                int t   = tok[e * T_TOK + gr];
                size_t base = (size_t)t * H_DIM + h0;
#pragma unroll
                for (int nf = 0; nf < 4; nf++)
                    atomicAdd(&out[base + wn * 64 + nf * 16 + l15], acc[mf][nf][j] * w);
            }
        }
}

extern "C" void kernel_launch(void* const* d_in, const int* in_sizes, int n_in,
                              void* d_out, int out_size, void* d_ws, size_t ws_size,
                              hipStream_t stream)
{
    const float* x  = (const float*)d_in[0];
    const float* rw = (const float*)d_in[1];
    const float* wg = (const float*)d_in[2];
    const float* wu = (const float*)d_in[3];
    const float* wd = (const float*)d_in[4];
    float* out = (float*)d_out;

    char* ws = (char*)d_ws;
    int*   cnt       = (int*)(ws);                 // 8 ints
    int*   ntiles    = (int*)(ws + 32);
    int*   offs_pad  = (int*)(ws + 64);            // 9 ints
    int*   tile_e    = (int*)(ws + 256);           // NT_MAX ints
    int*   tile_row0 = (int*)(ws + 512);           // NT_MAX ints
    int*   tok       = (int*)(ws + 64 * 1024);     // E*T ints (64 KB)
    float* wts       = (float*)(ws + 128 * 1024);  // 64 KB
    u16*   xbf       = (u16*)(ws + 256 * 1024);    // 4 MB
    u16*   act       = (u16*)(ws + 4608 * 1024);   // 5120*2048*2 = 21 MB

    size_t need = 4608ull * 1024 + (size_t)MAX_SLOTS * I_DIM * 2;
    if (ws_size < need) return;

    hipMemsetAsync(cnt, 0, 32, stream);
    hipMemsetAsync(out, 0, (size_t)T_TOK * H_DIM * sizeof(float), stream);

    router_k<<<T_TOK, 64, 0, stream>>>(x, rw, cnt, tok, wts, xbf);
    prefix_k<<<1, 64, 0, stream>>>(cnt, offs_pad, tile_e, tile_row0, ntiles);
    gateup_k<<<NT_MAX * (I_DIM / 128), 256, 0, stream>>>(
        xbf, wg, wu, cnt, offs_pad, tile_e, tile_row0, ntiles, tok, act);
    down_k<<<NT_MAX * (H_DIM / 128), 256, 0, stream>>>(
        act, wd, cnt, offs_pad, tile_e, tile_row0, ntiles, tok, wts, out);
}